// Round 4
// baseline (1015.682 us; speedup 1.0000x reference)
//
#include <hip/hip_runtime.h>
#include <cstdint>
#include <cstddef>

// Problem constants
#define T_TOK 4096
#define DIM   1024
#define NEXP  8
#define HID   2730
#define HP2   2816          // hidden padded to 88*32 = 22*128
#define NB1   5632          // 2*HP2 rows (gate || up) in transposed B1
#define NPAIR (T_TOK*2)

typedef __attribute__((ext_vector_type(8))) short short8;
typedef __attribute__((ext_vector_type(4))) float f32x4;

// ws layout (bytes)
#define OFF_CNT   0UL
#define OFF_USE   64UL
#define OFF_Z     96UL
#define OFF_OFFS  160UL                                   // 8 ints (prefix offsets)
#define OFF_LIST  256UL                                   // 8*4096 ints
#define OFF_PAIRW 131328UL                                // 8192 floats
#define OFF_XB    164096UL                                // 4096*1024 bf16
#define OFF_H     (OFF_XB + 8388608UL)                    // 8192*2816 bf16 (slot-compacted)
#define OFF_B2    (OFF_H + 46137344UL)                    // 8*1024*2816 bf16
#define OFF_B1    (OFF_B2 + 46137344UL)                   // 8*5632*1024 bf16
#define OFF_OP    OFF_B1                                  // overlay: 8192*1024 bf16 (B1 dead after gemm1)

// prep grid partition
#define NR_BLK   1024                   // router: 4 tokens/block
#define NW1_BLK  5632                   // 8 e * 32 kt * 22 ht
#define NW2_BLK  5632                   // 8 e * 88 kt * 8 dt

__device__ __forceinline__ unsigned short f2bf(float f) {
    unsigned u = __float_as_uint(f);
    return (unsigned short)((u + 0x7FFFu + ((u >> 16) & 1u)) >> 16);
}

__device__ __forceinline__ void load_lds16(const void* g, void* l) {
    __builtin_amdgcn_global_load_lds(
        (const __attribute__((address_space(1))) void*)g,
        (__attribute__((address_space(3))) void*)l, 16, 0, 0);
}

struct __align__(8) us4 { unsigned short x, y, z, w; };

// ---------------------------------------------------------------------------
// Fused prep: router blocks + w1-transpose blocks + w2-transpose blocks.
// All branches are block-uniform (branch on blockIdx only).
// ---------------------------------------------------------------------------
__global__ __launch_bounds__(256) void prep_kernel(
    const float* __restrict__ x, const float* __restrict__ rw,
    const float* __restrict__ wg, const float* __restrict__ wu,
    const float* __restrict__ wd,
    int* __restrict__ counts, float* __restrict__ usage, float* __restrict__ zacc,
    int* __restrict__ lists, float* __restrict__ pairw,
    unsigned short* __restrict__ xb, unsigned short* __restrict__ B1,
    unsigned short* __restrict__ B2)
{
    __shared__ __align__(16) char smem[33024];
    const int tid = threadIdx.x;
    const int bid = blockIdx.x;

    if (bid < NR_BLK) {
        // ---------------- router (+ x -> bf16) ----------------
        float* s_rw  = (float*)smem;             // 8192 floats
        float* s_use = (float*)(smem + 32768);   // 8
        float* s_z   = (float*)(smem + 32800);   // 1
        for (int i = tid; i < DIM * NEXP; i += 256) s_rw[i] = rw[i];
        if (tid < NEXP) s_use[tid] = 0.f;
        if (tid == NEXP) s_z[0] = 0.f;
        __syncthreads();

        const int wave = tid >> 6, lane = tid & 63;
        const int t = bid * 4 + wave;

        float acc[NEXP];
        #pragma unroll
        for (int e = 0; e < NEXP; ++e) acc[e] = 0.f;
        #pragma unroll
        for (int j = 0; j < DIM / 64; ++j) {
            const int d = j * 64 + lane;
            const float xv = x[(size_t)t * DIM + d];
            xb[(size_t)t * DIM + d] = f2bf(xv);
            #pragma unroll
            for (int e = 0; e < NEXP; ++e) acc[e] = fmaf(xv, s_rw[d * NEXP + e], acc[e]);
        }
        #pragma unroll
        for (int e = 0; e < NEXP; ++e) {
            float v = acc[e];
            for (int off = 32; off > 0; off >>= 1) v += __shfl_down(v, off, 64);
            acc[e] = v;
        }
        if (lane == 0) {
            float l[NEXP];
            #pragma unroll
            for (int e = 0; e < NEXP; ++e) l[e] = acc[e];
            float m = l[0];
            #pragma unroll
            for (int e = 1; e < NEXP; ++e) m = fmaxf(m, l[e]);
            float se = 0.f;
            #pragma unroll
            for (int e = 0; e < NEXP; ++e) se += __expf(l[e] - m);
            const float lse = m + __logf(se);
            #pragma unroll
            for (int e = 0; e < NEXP; ++e) atomicAdd(&s_use[e], __expf(l[e] - m) / se);
            atomicAdd(s_z, lse * lse);
            int i0 = 0; float l0 = l[0];
            #pragma unroll
            for (int e = 1; e < NEXP; ++e) if (l[e] > l0) { l0 = l[e]; i0 = e; }
            int i1 = -1; float l1 = -1e30f;
            #pragma unroll
            for (int e = 0; e < NEXP; ++e) if (e != i0 && l[e] > l1) { l1 = l[e]; i1 = e; }
            const float p0 = 1.f / (1.f + __expf(l1 - l0));
            const float p1 = 1.f - p0;
            const int pos0 = atomicAdd(&counts[i0], 1);
            lists[i0 * T_TOK + pos0] = (t << 1);
            const int pos1 = atomicAdd(&counts[i1], 1);
            lists[i1 * T_TOK + pos1] = (t << 1) | 1;
            pairw[2 * t]     = p0;
            pairw[2 * t + 1] = p1;
        }
        __syncthreads();
        if (tid < NEXP) atomicAdd(&usage[tid], s_use[tid]);
        if (tid == NEXP) atomicAdd(zacc, s_z[0]);
    } else if (bid < NR_BLK + NW1_BLK) {
        // ---------------- w_gate/w_up transpose: [k][h] f32 -> [n][k] bf16 ----
        const int idx = bid - NR_BLK;
        const int e  = idx / 704;          // 32*22
        const int rem = idx % 704;
        const int kt = rem / 22, ht = rem % 22;
        const int k0 = kt * 32, h0 = ht * 128;

        unsigned short* sg = (unsigned short*)smem;        // [32][132]
        unsigned short* su = sg + 32 * 132;

        const size_t wb = (size_t)e * DIM * HID;
        const int rr = tid >> 5;           // 0..7
        const int c4 = (tid & 31) * 4;     // 0..124
        #pragma unroll
        for (int i = 0; i < 4; ++i) {
            const int r = rr + i * 8;
            const size_t rowb = wb + (size_t)(k0 + r) * HID;
            const int h = h0 + c4;
            float2 g0 = make_float2(0.f, 0.f), g1 = g0, u0 = g0, u1 = g0;
            if (h < HID)     { g0 = *(const float2*)(wg + rowb + h);     u0 = *(const float2*)(wu + rowb + h); }
            if (h + 2 < HID) { g1 = *(const float2*)(wg + rowb + h + 2); u1 = *(const float2*)(wu + rowb + h + 2); }
            us4 vg; vg.x = f2bf(g0.x); vg.y = f2bf(g0.y); vg.z = f2bf(g1.x); vg.w = f2bf(g1.y);
            us4 vu; vu.x = f2bf(u0.x); vu.y = f2bf(u0.y); vu.z = f2bf(u1.x); vu.w = f2bf(u1.y);
            *(us4*)&sg[r * 132 + c4] = vg;
            *(us4*)&su[r * 132 + c4] = vu;
        }
        __syncthreads();
        // threads [0,128): gate rows; [128,256): up rows. One thread = one
        // output row's full 64B (sector-coalesced).
        const int hl = tid & 127;
        const unsigned short* src = (tid < 128) ? sg : su;
        unsigned short* dst = B1 + ((size_t)e * NB1 + (tid < 128 ? 0 : HP2) + h0 + hl) * DIM + k0;
        #pragma unroll
        for (int q = 0; q < 8; ++q) {
            us4 v;
            v.x = src[(q * 4 + 0) * 132 + hl];
            v.y = src[(q * 4 + 1) * 132 + hl];
            v.z = src[(q * 4 + 2) * 132 + hl];
            v.w = src[(q * 4 + 3) * 132 + hl];
            *(us4*)(dst + q * 4) = v;
        }
    } else {
        // ---------------- w_down transpose: [h][d] f32 -> [d][h] bf16 --------
        const int idx = bid - NR_BLK - NW1_BLK;
        const int e  = idx / 704;          // 88*8
        const int rem = idx % 704;
        const int kt = rem / 8, dt = rem % 8;
        const int k0 = kt * 32, d0 = dt * 128;

        unsigned short* sd = (unsigned short*)smem;        // [32][132]
        const size_t wb = (size_t)e * HID * DIM;
        const int rr = tid >> 5;
        const int c4 = (tid & 31) * 4;
        #pragma unroll
        for (int i = 0; i < 4; ++i) {
            const int r = rr + i * 8;
            const int h = k0 + r;
            float4 v = make_float4(0.f, 0.f, 0.f, 0.f);
            if (h < HID) v = *(const float4*)(wd + wb + (size_t)h * DIM + d0 + c4);
            us4 o; o.x = f2bf(v.x); o.y = f2bf(v.y); o.z = f2bf(v.z); o.w = f2bf(v.w);
            *(us4*)&sd[r * 132 + c4] = o;
        }
        __syncthreads();
        if (tid < 128) {
            const int dl = tid;
            unsigned short* dst = B2 + ((size_t)e * DIM + d0 + dl) * HP2 + k0;
            #pragma unroll
            for (int q = 0; q < 8; ++q) {
                us4 v;
                v.x = sd[(q * 4 + 0) * 132 + dl];
                v.y = sd[(q * 4 + 1) * 132 + dl];
                v.z = sd[(q * 4 + 2) * 132 + dl];
                v.w = sd[(q * 4 + 3) * 132 + dl];
                *(us4*)(dst + q * 4) = v;
            }
        }
    }
}

__global__ void finalize_kernel(const int* __restrict__ counts,
                                const float* __restrict__ usage,
                                const float* __restrict__ zacc,
                                int* __restrict__ offs,
                                float* __restrict__ out)
{
    if (threadIdx.x == 0 && blockIdx.x == 0) {
        int o = 0;
        for (int e = 0; e < NEXP; ++e) { offs[e] = o; o += counts[e]; }
        float s = 0.f;
        for (int e = 0; e < NEXP; ++e) {
            const float u = usage[e] / (float)T_TOK;
            s += u * u;
        }
        out[(size_t)T_TOK * DIM]     = (float)NEXP * s;
        out[(size_t)T_TOK * DIM + 1] = zacc[0] / (float)T_TOK;
    }
}

// ---------------------------------------------------------------------------
// GEMM1 (MFMA, swizzled LDS): h[slot,:] = silu(Xe@Wg)*(Xe@Wu), 128x128x32
// grid: (x=row-tiles, y=n-tiles, z=expert) -> same-B blocks dispatch-adjacent
// ---------------------------------------------------------------------------
__global__ __launch_bounds__(256, 2) void gemm1_kernel(
    const unsigned short* __restrict__ xb, const unsigned short* __restrict__ B1,
    const int* __restrict__ counts, const int* __restrict__ offs,
    const int* __restrict__ lists, unsigned short* __restrict__ h)
{
    const int e = blockIdx.z;
    const int cnt = counts[e];
    const int row0 = blockIdx.x * 128;
    if (row0 >= cnt) return;
    const int off = offs[e];
    const int n0 = blockIdx.y * 128;

    __shared__ unsigned short s1[12288];   // 24 KB arena: A | Bg | Bu
    __shared__ int s_pr[128];
    unsigned short* sA  = s1;
    unsigned short* sBg = s1 + 4096;
    unsigned short* sBu = s1 + 8192;

    const int tid = threadIdx.x;
    const int w = tid >> 6, lane = tid & 63;
    if (tid < 128) {
        const int r = row0 + tid;
        s_pr[tid] = (r < cnt) ? lists[e * T_TOK + r] : -1;
    }
    __syncthreads();

    const int rA = tid >> 2, kb = tid & 3;
    const int kbs = (kb ^ ((rA >> 1) & 3)) * 8;
    const int pr0 = s_pr[rA], pr1 = s_pr[rA + 64];
    const unsigned short* agp0 = xb + (size_t)(max(pr0, 0) >> 1) * DIM + kbs;
    const unsigned short* agp1 = xb + (size_t)(max(pr1, 0) >> 1) * DIM + kbs;
    const unsigned short* bgp0 = B1 + ((size_t)e * NB1 + n0 + rA) * DIM + kbs;
    const unsigned short* bgp1 = bgp0 + (size_t)64 * DIM;
    const unsigned short* bup0 = B1 + ((size_t)e * NB1 + HP2 + n0 + rA) * DIM + kbs;
    const unsigned short* bup1 = bup0 + (size_t)64 * DIM;

    char* sAb = (char*)sA; char* sBgb = (char*)sBg; char* sBub = (char*)sBu;
    void* ldsA0 = sAb + w * 1024;        void* ldsA1 = sAb + 4096 + w * 1024;
    void* ldsG0 = sBgb + w * 1024;       void* ldsG1 = sBgb + 4096 + w * 1024;
    void* ldsU0 = sBub + w * 1024;       void* ldsU1 = sBub + 4096 + w * 1024;

    f32x4 accg[4][4], accu[4][4];
    #pragma unroll
    for (int i = 0; i < 4; ++i)
        #pragma unroll
        for (int j = 0; j < 4; ++j) { accg[i][j] = (f32x4)0.f; accu[i][j] = (f32x4)0.f; }

    const int wm = w & 1, wn = w >> 1;
    const int fm = lane & 15, fq = lane >> 4;
    const int kq = (fq ^ ((fm >> 1) & 3)) * 8;

    for (int kt = 0; kt < DIM / 32; ++kt) {
        const int k0 = kt * 32;
        load_lds16(agp0 + k0, ldsA0);
        load_lds16(agp1 + k0, ldsA1);
        load_lds16(bgp0 + k0, ldsG0);
        load_lds16(bgp1 + k0, ldsG1);
        load_lds16(bup0 + k0, ldsU0);
        load_lds16(bup1 + k0, ldsU1);
        __syncthreads();

        short8 a[4], bg[4], bu[4];
        #pragma unroll
        for (int i = 0; i < 4; ++i) {
            a[i]  = *(const short8*)&sA[(wm * 64 + i * 16 + fm) * 32 + kq];
            bg[i] = *(const short8*)&sBg[(wn * 64 + i * 16 + fm) * 32 + kq];
            bu[i] = *(const short8*)&sBu[(wn * 64 + i * 16 + fm) * 32 + kq];
        }
        #pragma unroll
        for (int i = 0; i < 4; ++i)
            #pragma unroll
            for (int j = 0; j < 4; ++j) {
                accg[i][j] = __builtin_amdgcn_mfma_f32_16x16x32_bf16(a[i], bg[j], accg[i][j], 0, 0, 0);
                accu[i][j] = __builtin_amdgcn_mfma_f32_16x16x32_bf16(a[i], bu[j], accu[i][j], 0, 0, 0);
            }
        __syncthreads();
    }

    // epilogue: silu(g)*u -> LDS bounce (16x64 subtile, stride 72) -> 16B stores
    unsigned short* wbuf = s1 + w * 1152;
    const int rrow = lane >> 2, cq = (lane & 3) * 16;
    #pragma unroll
    for (int i = 0; i < 4; ++i) {
        #pragma unroll
        for (int j = 0; j < 4; ++j)
            #pragma unroll
            for (int reg = 0; reg < 4; ++reg) {
                const float g = accg[i][j][reg];
                const float u = accu[i][j][reg];
                const float s = g / (1.f + __expf(-g));
                wbuf[(fq * 4 + reg) * 72 + j * 16 + fm] = f2bf(s * u);
            }
        const int rl = wm * 64 + i * 16 + rrow;
        if (row0 + rl < cnt) {
            unsigned short* dst = h + (size_t)(off + row0 + rl) * HP2 + n0 + wn * 64 + cq;
            const short8 v0 = *(const short8*)&wbuf[rrow * 72 + cq];
            const short8 v1 = *(const short8*)&wbuf[rrow * 72 + cq + 8];
            *(short8*)dst = v0;
            *(short8*)(dst + 8) = v1;
        }
    }
}

// ---------------------------------------------------------------------------
// GEMM2 (MFMA, swizzled LDS): op[pr,:] = h_slot @ Wd, 128x128x32, K=2816
// ---------------------------------------------------------------------------
__global__ __launch_bounds__(256, 2) void gemm2_kernel(
    const unsigned short* __restrict__ h, const unsigned short* __restrict__ B2,
    const int* __restrict__ counts, const int* __restrict__ offs,
    const int* __restrict__ lists, unsigned short* __restrict__ op)
{
    const int e = blockIdx.z;
    const int cnt = counts[e];
    const int row0 = blockIdx.x * 128;
    if (row0 >= cnt) return;
    const int off = offs[e];
    const int n0 = blockIdx.y * 128;

    __shared__ unsigned short s2[8192];
    __shared__ int s_pr[128];
    unsigned short* sA = s2;
    unsigned short* sB = s2 + 4096;

    const int tid = threadIdx.x;
    const int w = tid >> 6, lane = tid & 63;
    if (tid < 128) {
        const int r = row0 + tid;
        s_pr[tid] = (r < cnt) ? lists[e * T_TOK + r] : -1;
    }
    __syncthreads();

    const int rA = tid >> 2, kb = tid & 3;
    const int kbs = (kb ^ ((rA >> 1) & 3)) * 8;
    const unsigned short* agp0 = h + (size_t)(off + row0 + rA) * HP2 + kbs;
    const unsigned short* agp1 = agp0 + (size_t)64 * HP2;
    const unsigned short* bp0 = B2 + ((size_t)e * DIM + n0 + rA) * HP2 + kbs;
    const unsigned short* bp1 = bp0 + (size_t)64 * HP2;

    char* sAb = (char*)sA; char* sBb = (char*)sB;
    void* ldsA0 = sAb + w * 1024;  void* ldsA1 = sAb + 4096 + w * 1024;
    void* ldsB0 = sBb + w * 1024;  void* ldsB1 = sBb + 4096 + w * 1024;

    f32x4 acc[4][4];
    #pragma unroll
    for (int i = 0; i < 4; ++i)
        #pragma unroll
        for (int j = 0; j < 4; ++j) acc[i][j] = (f32x4)0.f;

    const int wm = w & 1, wn = w >> 1;
    const int fm = lane & 15, fq = lane >> 4;
    const int kq = (fq ^ ((fm >> 1) & 3)) * 8;

    for (int kt = 0; kt < HP2 / 32; ++kt) {
        const int k0 = kt * 32;
        load_lds16(agp0 + k0, ldsA0);
        load_lds16(agp1 + k0, ldsA1);
        load_lds16(bp0 + k0, ldsB0);
        load_lds16(bp1 + k0, ldsB1);
        __syncthreads();

        short8 a[4], b[4];
        #pragma unroll
        for (int i = 0; i < 4; ++i) {
            a[i] = *(const short8*)&sA[(wm * 64 + i * 16 + fm) * 32 + kq];
            b[i] = *(const short8*)&sB[(wn * 64 + i * 16 + fm) * 32 + kq];
        }
        #pragma unroll
        for (int i = 0; i < 4; ++i)
            #pragma unroll
            for (int j = 0; j < 4; ++j)
                acc[i][j] = __builtin_amdgcn_mfma_f32_16x16x32_bf16(a[i], b[j], acc[i][j], 0, 0, 0);
        __syncthreads();
    }

    unsigned short* wbuf = s2 + w * 1152;
    const int rrow = lane >> 2, cq = (lane & 3) * 16;
    #pragma unroll
    for (int i = 0; i < 4; ++i) {
        #pragma unroll
        for (int j = 0; j < 4; ++j)
            #pragma unroll
            for (int reg = 0; reg < 4; ++reg)
                wbuf[(fq * 4 + reg) * 72 + j * 16 + fm] = f2bf(acc[i][j][reg]);
        const int rl = wm * 64 + i * 16 + rrow;
        const int pr = s_pr[rl];
        if (pr >= 0) {
            unsigned short* dst = op + (size_t)pr * DIM + n0 + wn * 64 + cq;
            const short8 v0 = *(const short8*)&wbuf[rrow * 72 + cq];
            const short8 v1 = *(const short8*)&wbuf[rrow * 72 + cq + 8];
            *(short8*)dst = v0;
            *(short8*)(dst + 8) = v1;
        }
    }
}

// ---------------------------------------------------------------------------
// Combine: out[t] = w0*op[2t] + w1*op[2t+1]  (op bf16 -> out f32)
// ---------------------------------------------------------------------------
__global__ __launch_bounds__(256) void combine_kernel(
    const unsigned short* __restrict__ op, const float* __restrict__ pairw,
    float* __restrict__ out)
{
    const int f = blockIdx.x * 256 + threadIdx.x;
    const int t = f >> 8;
    const int c = f & 255;
    const float w0 = pairw[2 * t], w1 = pairw[2 * t + 1];
    const us4 a = ((const us4*)op)[(size_t)(2 * t) * (DIM / 4) + c];
    const us4 b = ((const us4*)op)[(size_t)(2 * t + 1) * (DIM / 4) + c];
    float4 r;
    r.x = w0 * __uint_as_float((unsigned)a.x << 16) + w1 * __uint_as_float((unsigned)b.x << 16);
    r.y = w0 * __uint_as_float((unsigned)a.y << 16) + w1 * __uint_as_float((unsigned)b.y << 16);
    r.z = w0 * __uint_as_float((unsigned)a.z << 16) + w1 * __uint_as_float((unsigned)b.z << 16);
    r.w = w0 * __uint_as_float((unsigned)a.w << 16) + w1 * __uint_as_float((unsigned)b.w << 16);
    ((float4*)out)[f] = r;
}

extern "C" void kernel_launch(void* const* d_in, const int* in_sizes, int n_in,
                              void* d_out, int out_size, void* d_ws, size_t ws_size,
                              hipStream_t stream)
{
    const float* x  = (const float*)d_in[0];
    const float* rw = (const float*)d_in[1];
    const float* wg = (const float*)d_in[2];
    const float* wu = (const float*)d_in[3];
    const float* wd = (const float*)d_in[4];
    float* out = (float*)d_out;
    char* ws = (char*)d_ws;

    int*   counts = (int*)(ws + OFF_CNT);
    float* usage  = (float*)(ws + OFF_USE);
    float* zacc   = (float*)(ws + OFF_Z);
    int*   offs   = (int*)(ws + OFF_OFFS);
    int*   lists  = (int*)(ws + OFF_LIST);
    float* pairw  = (float*)(ws + OFF_PAIRW);
    unsigned short* xb  = (unsigned short*)(ws + OFF_XB);
    unsigned short* hb  = (unsigned short*)(ws + OFF_H);
    unsigned short* B2  = (unsigned short*)(ws + OFF_B2);
    unsigned short* B1  = (unsigned short*)(ws + OFF_B1);
    unsigned short* op  = (unsigned short*)(ws + OFF_OP);

    hipMemsetAsync(ws, 0, 128, stream);

    prep_kernel<<<NR_BLK + NW1_BLK + NW2_BLK, 256, 0, stream>>>(
        x, rw, wg, wu, wd, counts, usage, zacc, lists, pairw, xb, B1, B2);
    finalize_kernel<<<1, 64, 0, stream>>>(counts, usage, zacc, offs, out);

    gemm1_kernel<<<dim3(T_TOK / 128, HP2 / 128, NEXP), 256, 0, stream>>>(xb, B1, counts, offs, lists, hb);
    gemm2_kernel<<<dim3(T_TOK / 128, DIM / 128, NEXP), 256, 0, stream>>>(hb, B2, counts, offs, lists, op);

    combine_kernel<<<(T_TOK * DIM / 4) / 256, 256, 0, stream>>>(op, pairw, out);
}